// Round 8
// baseline (466.543 us; speedup 1.0000x reference)
//
#include <hip/hip_runtime.h>
#include <hip/hip_bf16.h>
#include <math.h>

#define DEV __device__ __forceinline__

constexpr int B=8, C=64, DIM=256, HID=128, S=64, NH=16, HD=4, LPIX=784;

constexpr size_t OFF_X1O = 0;                                   // B*C*L
constexpr size_t OFF_T1  = OFF_X1O + (size_t)B*C*LPIX;          // B*HID*L
constexpr size_t OFF_T2  = OFF_T1  + (size_t)B*HID*LPIX;        // B*C*L
constexpr size_t OFF_XA  = OFF_T2  + (size_t)B*C*LPIX;          // B*DIM*L
constexpr size_t OFF_BC1 = OFF_XA  + (size_t)B*DIM*LPIX;        // B*192*L
constexpr size_t OFF_BC2 = OFF_BC1 + (size_t)B*192*LPIX;        // B*192*L
constexpr size_t OFF_WGT = OFF_BC2 + (size_t)B*192*LPIX;        // B*S*L
constexpr size_t OFF_H   = OFF_WGT + (size_t)B*S*LPIX;          // B*C*S (partial 0)
constexpr size_t OFF_H2  = OFF_H   + (size_t)B*C*S;             // B*C*S (partial 1)
constexpr size_t OFF_HO  = OFF_H2  + (size_t)B*C*S;             // B*C*S
constexpr size_t OFF_QKV = OFF_HO  + (size_t)B*C*S;             // 3*B*NH*L*HD
constexpr size_t OFF_O   = OFF_QKV + (size_t)3*B*NH*LPIX*HD;    // B*L*C   (atomic acc)
constexpr size_t OFF_LS  = OFF_O   + (size_t)B*LPIX*C;          // B*NH*L  (atomic acc, contiguous with OFF_O)
constexpr size_t OFF_MID = OFF_LS  + (size_t)B*NH*LPIX;         // B*HID*L

DEV float bnorm(float x, const float* p, int c, int nc){
  float g=p[c], bb=p[nc+c], m=p[2*nc+c], v=p[3*nc+c];
  return (x-m)*(g*rsqrtf(v+1e-5f))+bb;
}

// ---- branch 1 ----
__global__ void k_dw1(const float* X, const float* w, const float* bias, const float* bnp, float* out){
  int idx = blockIdx.x*256+threadIdx.x; if(idx>=B*C*LPIX) return;
  int l=idx%LPIX, c=(idx/LPIX)%C, b=idx/(LPIX*C);
  int y=l/28, x=l%28;
  const float* xp = X + ((size_t)(b*DIM+c))*LPIX;
  float s = bias[c];
  for(int ky=0;ky<7;ky++){ int iy=y+ky-3; if(iy<0||iy>=28) continue;
    for(int kx=0;kx<7;kx++){ int ix=x+kx-3; if(ix<0||ix>=28) continue;
      s += xp[(size_t)iy*28+ix]*w[(size_t)c*49+ky*7+kx]; } }
  out[idx] = bnorm(s,bnp,c,C);
}

__global__ void k_star(const float* x1o, const float* f1w,const float* f1b,const float* f2w,const float* f2b,float* t1){
  int idx = blockIdx.x*256+threadIdx.x; if(idx>=B*(HID/4)*LPIX) return;
  int l=idx%LPIX, jg=(idx/LPIX)%(HID/4), b=idx/(LPIX*(HID/4));
  int j0=jg*4;
  const float* xp = x1o + (size_t)b*C*LPIX + l;
  float a[4], g[4];
  for(int t=0;t<4;t++){ a[t]=f1b[j0+t]; g[t]=f2b[j0+t]; }
  for(int c=0;c<C;c++){
    float xv = xp[(size_t)c*LPIX];
    for(int t=0;t<4;t++){ a[t]+=f1w[(size_t)(j0+t)*C+c]*xv; g[t]+=f2w[(size_t)(j0+t)*C+c]*xv; }
  }
  for(int t=0;t<4;t++){
    float av = fminf(fmaxf(a[t],0.f),6.f);
    t1[((size_t)(b*HID+j0+t))*LPIX + l] = av*g[t];
  }
}

__global__ void k_gproj(const float* t1, const float* gw,const float* gb,const float* bnp,float* t2){
  int idx = blockIdx.x*256+threadIdx.x; if(idx>=B*(C/4)*LPIX) return;
  int l=idx%LPIX, cg=(idx/LPIX)%(C/4), b=idx/(LPIX*(C/4));
  int c0=cg*4;
  const float* tp = t1 + (size_t)b*HID*LPIX + l;
  float s[4]; for(int t=0;t<4;t++) s[t]=gb[c0+t];
  for(int j=0;j<HID;j++){
    float xv = tp[(size_t)j*LPIX];
    for(int t=0;t<4;t++) s[t]+=gw[(size_t)(c0+t)*HID+j]*xv;
  }
  for(int t=0;t<4;t++) t2[((size_t)(b*C+c0+t))*LPIX + l]=bnorm(s[t],bnp,c0+t,C);
}

__global__ void k_dw2(const float* t2,const float* w,const float* bias,float* xa){
  int idx = blockIdx.x*256+threadIdx.x; if(idx>=B*C*LPIX) return;
  int l=idx%LPIX, c=(idx/LPIX)%C, b=idx/(LPIX*C);
  int y=l/28, x=l%28;
  const float* tp = t2 + ((size_t)(b*C+c))*LPIX;
  float s=bias[c];
  for(int ky=0;ky<7;ky++){ int iy=y+ky-3; if(iy<0||iy>=28) continue;
    for(int kx=0;kx<7;kx++){ int ix=x+kx-3; if(ix<0||ix>=28) continue;
      s += tp[(size_t)iy*28+ix]*w[(size_t)c*49+ky*7+kx]; } }
  xa[((size_t)(b*DIM+c))*LPIX + l] = s;
}

// ---- branch 2 (fully fused: maxpool3 + blurpool + MRA convs + sigmoid + upsample-mul) ----
DEV int refl(int p){ int k=p-1; if(k<0)k=-k; if(k>27)k=54-k; return k; }

__global__ void k_branch2(const float* X, const float* h1w,const float* v1w,const float* h2w,const float* v2w,
                          const float* bnp, float* xa){
  int bc = blockIdx.x; int c = bc & 63, b = bc >> 6;
  const float* xp = X + ((size_t)(b*DIM+64+c))*LPIX;
  __shared__ float xs[LPIX];
  __shared__ float mp[LPIX];
  __shared__ float xt[100];
  __shared__ float attv[100];
  for(int i=threadIdx.x;i<LPIX;i+=256) xs[i]=xp[i];
  __syncthreads();
  for(int i=threadIdx.x;i<LPIX;i+=256){
    int y=i/28, x=i%28;
    float m=-1e30f;
    for(int dy=-1;dy<=1;dy++){ int iy=y+dy; if(iy<0||iy>=28) continue;
      for(int dx=-1;dx<=1;dx++){ int ix=x+dx; if(ix<0||ix>=28) continue;
        m=fmaxf(m,xs[iy*28+ix]); } }
    mp[i]=m;
  }
  __syncthreads();
  if(threadIdx.x<100){
    int ii=threadIdx.x/10, j=threadIdx.x%10;
    const float fw[4]={0.125f,0.375f,0.375f,0.125f};
    float s=0;
    for(int ky=0;ky<4;ky++){ int rr=refl(3*ii+ky);
      for(int kx=0;kx<4;kx++){ int cc=refl(3*j+kx);
        s += fw[ky]*fw[kx]*mp[rr*28+cc]; } }
    xt[threadIdx.x]=s;
  }
  __syncthreads();
  if(threadIdx.x<100){
    int r=threadIdx.x/10, j=threadIdx.x%10;
    float s=0;
    for(int kh=0;kh<11;kh++){ int a=r+kh-5; if(a<0||a>=10) continue;
      for(int kw=0;kw<3;kw++){ int b2=j+kw-1; if(b2<0||b2>=10) continue;
        s+=xt[a*10+b2]*h1w[(size_t)c*33+kh*3+kw]; } }
    for(int kh=0;kh<3;kh++){ int a=r+kh-1; if(a<0||a>=10) continue;
      for(int kw=0;kw<11;kw++){ int b2=j+kw-5; if(b2<0||b2>=10) continue;
        s+=xt[a*10+b2]*v1w[(size_t)c*33+kh*11+kw]; } }
    { int t=20*r+j; int r2=t/19, j2=t%19;
      for(int kh=0;kh<11;kh++){ int a=r2+kh-5; if(a<0||a>=10) continue;
        for(int kw=0;kw<3;kw++){ int b2=j2+kw-1; if(b2<0||b2>=19) continue;
          int i2=19*a+b2; int row=i2/20, col=i2%20;
          if(col<10) s+=xt[row*10+col]*h2w[(size_t)c*33+kh*3+kw]; } } }
    { int t=20*j+r; int p=t%19, q=t/19;
      for(int kh=0;kh<3;kh++){ int a=p+kh-1; if(a<0||a>=19) continue;
        for(int kw=0;kw<11;kw++){ int b2=q+kw-5; if(b2<0||b2>=10) continue;
          int i2=19*b2+a; int row=i2/20, col=i2%20;
          if(col<10) s+=xt[col*10+row]*v2w[(size_t)c*33+kh*11+kw]; } } }
    s = bnorm(s,bnp,c,C);
    attv[threadIdx.x] = 1.f/(1.f+__expf(-s));
  }
  __syncthreads();
  float* dst = xa + ((size_t)(b*DIM+64+c))*LPIX;
  for(int i=threadIdx.x;i<LPIX;i+=256){
    int y=i/28, x=i%28;
    float a = attv[((y*10)/28)*10 + (x*10)/28];
    dst[i] = xs[i]*a;
  }
}

// ---- branch 3 ----
__global__ void k_bcdt(const float* X, const float* w, float* bc1){
  int idx = blockIdx.x*256+threadIdx.x; if(idx>=B*48*LPIX) return;
  int l=idx%LPIX, og=(idx/LPIX)%48, b=idx/(LPIX*48);
  int o0=og*4;
  const float* xp = X + ((size_t)(b*DIM+128))*LPIX + l;
  float s[4]={0,0,0,0};
  for(int c=0;c<C;c++){ float xv=xp[(size_t)c*LPIX];
    for(int t=0;t<4;t++) s[t]+=w[(size_t)(o0+t)*C+c]*xv; }
  for(int t=0;t<4;t++) bc1[((size_t)(b*192+o0+t))*LPIX+l]=s[t];
}

__global__ void k_ssddw(const float* bc1, const float* w, float* bc2){
  int idx = blockIdx.x*256+threadIdx.x; if(idx>=B*192*LPIX) return;
  int l=idx%LPIX, ch=(idx/LPIX)%192, b=idx/(LPIX*192);
  int y=l/28, x=l%28;
  const float* p = bc1 + (size_t)(b*192+ch)*LPIX;
  float s=0;
  for(int ky=0;ky<3;ky++){ int iy=y+ky-1; if(iy<0||iy>=28) continue;
    for(int kx=0;kx<3;kx++){ int ix=x+kx-1; if(ix<0||ix>=28) continue;
      s += p[(size_t)iy*28+ix]*w[(size_t)ch*9+ky*3+kx]; } }
  bc2[idx]=s;
}

__global__ void k_ssd_softmax(const float* bc2, float* wgt){
  int bs = blockIdx.x; int b=bs>>6, s_=bs&63;
  const float* dt = bc2 + ((size_t)(b*192+128+s_))*LPIX;
  const float* Bm = bc2 + ((size_t)(b*192+s_))*LPIX;
  __shared__ float row[LPIX];
  __shared__ float red[256];
  int t=threadIdx.x;
  float mx=-1e30f;
  for(int l=t;l<LPIX;l+=256){ float v=dt[l]; row[l]=v; mx=fmaxf(mx,v); }
  red[t]=mx; __syncthreads();
  for(int o=128;o>0;o>>=1){ if(t<o) red[t]=fmaxf(red[t],red[t+o]); __syncthreads(); }
  mx=red[0]; __syncthreads();
  float sum=0;
  for(int l=t;l<LPIX;l+=256){ float e=__expf(row[l]-mx); row[l]=e; sum+=e; }
  red[t]=sum; __syncthreads();
  for(int o=128;o>0;o>>=1){ if(t<o) red[t]+=red[t+o]; __syncthreads(); }
  float inv=1.f/red[0];
  for(int l=t;l<LPIX;l+=256) wgt[((size_t)(b*S+s_))*LPIX+l] = row[l]*inv*Bm[l];
}

// h[b,c,s] = sum_l X3[b,c,l]*wgt[b,s,l] — LDS-tiled GEMM.
// grid = B * 16 tiles * 2 L-halves = 256 blocks; block computes a 16x16 (c,s) tile over one L-half.
__global__ void k_h(const float* __restrict__ X, const float* __restrict__ wgt,
                    float* __restrict__ h0, float* __restrict__ h1){
  int sub = blockIdx.x & 31; int b = blockIdx.x >> 5;
  int tile = sub >> 1, half = sub & 1;
  int ct = (tile>>2)*16, st = (tile&3)*16;
  int l0 = half*392;
  __shared__ float Xs[16][393];
  __shared__ float Ws[16][393];
  for(int i=threadIdx.x;i<16*392;i+=256){
    int r=i/392, col=i%392;
    Xs[r][col] = X[((size_t)(b*DIM+128+ct+r))*LPIX + l0 + col];
    Ws[r][col] = wgt[((size_t)(b*S+st+r))*LPIX + l0 + col];
  }
  __syncthreads();
  int tc = threadIdx.x>>4, ts = threadIdx.x&15;
  float acc=0;
  #pragma unroll 4
  for(int l=0;l<392;l++) acc += Xs[tc][l]*Ws[ts][l];
  float* dst = half ? h1 : h0;
  dst[((size_t)(b*C+ct+tc))*S + st+ts] = acc;
}

__global__ void k_mixho(const float* h0, const float* h1, const float* hzw, const float* Dp, const float* outw, float* ho){
  int b = blockIdx.x >> 3, st = (blockIdx.x & 7) * 8;
  __shared__ float hs2[C][8];
  __shared__ float g1s[C][8];
  for(int i=threadIdx.x;i<C*8;i+=256){
    int k=i>>3, si=i&7;
    size_t off = ((size_t)(b*C+k))*S + st + si;
    hs2[k][si] = h0[off] + h1[off];
  }
  __syncthreads();
  float D = Dp[0];
  for(int i=threadIdx.x;i<C*8;i+=256){
    int c=i>>3, si=i&7;
    float hv=0, zv=0;
    for(int k=0;k<C;k++){ float x=hs2[k][si]; hv+=hzw[(size_t)c*C+k]*x; zv+=hzw[(size_t)(C+c)*C+k]*x; }
    float sil = zv/(1.f+__expf(-zv));
    g1s[c][si]=hv*sil+hv*D;
  }
  __syncthreads();
  for(int i=threadIdx.x;i<C*8;i+=256){
    int c=i>>3, si=i&7;
    float acc=0;
    for(int k=0;k<C;k++) acc+=outw[(size_t)c*C+k]*g1s[k][si];
    ho[((size_t)(b*C+c))*S + st + si]=acc;
  }
}

__global__ void k_x3(const float* ho, const float* bc2, float* xa){
  int idx = blockIdx.x*256+threadIdx.x; if(idx>=B*C*LPIX) return;
  int l=idx%LPIX, c=(idx/LPIX)%C, b=idx/(LPIX*C);
  const float* hp = ho + (size_t)(b*C+c)*S;
  const float* cm = bc2 + ((size_t)(b*192+64))*LPIX + l;
  float acc=0;
  for(int s_=0;s_<S;s_++) acc += hp[s_]*cm[(size_t)s_*LPIX];
  xa[((size_t)(b*DIM+128+c))*LPIX + l] = acc;
}

// ---- branch 4 ----
__global__ void k_qkv(const float* X, const float* w, float* qkvb){
  int idx = blockIdx.x*256+threadIdx.x; if(idx>=B*48*LPIX) return;
  int l=idx%LPIX, og=(idx/LPIX)%48, b=idx/(LPIX*48);
  int o0=og*4;
  const float* xp = X + ((size_t)(b*DIM+192))*LPIX + l;
  float s[4]={0,0,0,0};
  for(int c=0;c<C;c++){ float xv=xp[(size_t)c*LPIX];
    for(int t=0;t<4;t++) s[t]+=w[(size_t)(o0+t)*C+c]*xv; }
  int which=o0>>6, rem=o0&63, head=rem>>2;
  float4* dst = (float4*)(qkvb + (size_t)which*B*NH*LPIX*HD + ((size_t)((b*NH+head)*LPIX+l))*HD);
  *dst = make_float4(s[0],s[1],s[2],s[3]);
}

// m-split partial attention, 4 m-segments, atomic accumulation into zeroed obuf/lsb.
// grid = B*NH*8: [bh][rowseg(2)][mseg(4)].
__global__ void k_attn(const float* __restrict__ qkvb, float* __restrict__ obuf, float* __restrict__ lsb){
  int bh  = blockIdx.x >> 3;
  int sub = blockIdx.x & 7;
  int seg = sub >> 2;
  int ms  = sub & 3;
  int b = bh>>4, h = bh&15;
  const float4* q4 = (const float4*)(qkvb + (size_t)bh*LPIX*HD);
  const float4* k4 = (const float4*)(qkvb + (size_t)(B*NH + bh)*LPIX*HD) + ms*196;
  const float4* v4 = (const float4*)(qkvb + (size_t)(2*B*NH + bh)*LPIX*HD) + ms*196;
  __shared__ float4 ks[196], vs[196];
  for(int i=threadIdx.x;i<196;i+=256){ ks[i]=k4[i]; vs[i]=v4[i]; }
  __syncthreads();
  int r0 = seg*392;
  int ra = r0 + threadIdx.x;
  int rb = ra + 256;
  bool hasB = (threadIdx.x < 392-256);
  float4 qa = q4[ra];
  float4 qb = q4[hasB ? rb : ra];
  qa.x*=0.5f; qa.y*=0.5f; qa.z*=0.5f; qa.w*=0.5f;
  qb.x*=0.5f; qb.y*=0.5f; qb.z*=0.5f; qb.w*=0.5f;
  float lsA=0,a0=0,a1=0,a2=0,a3=0;
  float lsB=0,b0=0,b1=0,b2=0,b3=0;
  #pragma unroll 4
  for(int m=0;m<196;m++){
    float4 kv = ks[m]; float4 vv = vs[m];
    float sa = qa.x*kv.x+qa.y*kv.y+qa.z*kv.z+qa.w*kv.w;
    float sb = qb.x*kv.x+qb.y*kv.y+qb.z*kv.z+qb.w*kv.w;
    float pa = __expf(sa), pb = __expf(sb);
    lsA+=pa; a0+=pa*vv.x; a1+=pa*vv.y; a2+=pa*vv.z; a3+=pa*vv.w;
    lsB+=pb; b0+=pb*vv.x; b1+=pb*vv.y; b2+=pb*vv.z; b3+=pb*vv.w;
  }
  float* op = obuf + ((size_t)(b*LPIX+ra))*C + h*4;
  atomicAdd(op+0,a0); atomicAdd(op+1,a1); atomicAdd(op+2,a2); atomicAdd(op+3,a3);
  atomicAdd(&lsb[(size_t)bh*LPIX + ra], lsA);
  if(hasB){
    op = obuf + ((size_t)(b*LPIX+rb))*C + h*4;
    atomicAdd(op+0,b0); atomicAdd(op+1,b1); atomicAdd(op+2,b2); atomicAdd(op+3,b3);
    atomicAdd(&lsb[(size_t)bh*LPIX + rb], lsB);
  }
}

// normalize + proj + residual + BN
__global__ void k_x4(const float* X, const float* obuf, const float* lsb,
                     const float* projw, const float* bnp, float* xa){
  int idx = blockIdx.x*256+threadIdx.x; if(idx>=B*(C/4)*LPIX) return;
  int l=idx%LPIX, cg=(idx/LPIX)%(C/4), b=idx/(LPIX*(C/4));
  int c0=cg*4;
  const float* p0 = obuf + ((size_t)(b*LPIX+l))*C;
  float s[4]={0,0,0,0};
  for(int h=0;h<NH;h++){
    float iv = 1.f/lsb[((size_t)(b*NH+h))*LPIX + l];
    for(int kk=0;kk<4;kk++){
      int k = h*4+kk;
      float ov = p0[k]*iv;
      for(int t=0;t<4;t++) s[t]+=projw[(size_t)(c0+t)*C+k]*ov;
    }
  }
  for(int t=0;t<4;t++){
    float v = s[t] + X[((size_t)(b*DIM+192+c0+t))*LPIX + l];
    xa[((size_t)(b*DIM+192+c0+t))*LPIX + l] = bnorm(v,bnp,c0+t,C);
  }
}

// ---- merge MLP ----
__global__ void k_mid(const float* xa, const float* m1w, const float* bnp, float* mid){
  int idx = blockIdx.x*256+threadIdx.x; if(idx>=B*(HID/4)*LPIX) return;
  int l=idx%LPIX, jg=(idx/LPIX)%(HID/4), b=idx/(LPIX*(HID/4));
  int j0=jg*4;
  const float* xp = xa + (size_t)b*DIM*LPIX + l;
  float s[4]={0,0,0,0};
  for(int c=0;c<DIM;c++){ float xv=xp[(size_t)c*LPIX];
    for(int t=0;t<4;t++) s[t]+=m1w[(size_t)(j0+t)*DIM+c]*xv; }
  for(int t=0;t<4;t++)
    mid[((size_t)(b*HID+j0+t))*LPIX + l] = fmaxf(bnorm(s[t],bnp,j0+t,HID),0.f);
}

__global__ void k_out(const float* X, const float* mid, const float* m2w, const float* bnp, float* out){
  int idx = blockIdx.x*256+threadIdx.x; if(idx>=B*(DIM/4)*LPIX) return;
  int l=idx%LPIX, cg=(idx/LPIX)%(DIM/4), b=idx/(LPIX*(DIM/4));
  int c0=cg*4;
  const float* mp_ = mid + (size_t)b*HID*LPIX + l;
  float s[4]={0,0,0,0};
  for(int j=0;j<HID;j++){ float mv=mp_[(size_t)j*LPIX];
    for(int t=0;t<4;t++) s[t]+=m2w[(size_t)(c0+t)*HID+j]*mv; }
  for(int t=0;t<4;t++){
    size_t oi = ((size_t)(b*DIM+c0+t))*LPIX + l;
    out[oi] = bnorm(s[t],bnp,c0+t,DIM) + X[oi];
  }
}

extern "C" void kernel_launch(void* const* d_in, const int* in_sizes, int n_in,
                              void* d_out, int out_size, void* d_ws, size_t ws_size,
                              hipStream_t stream) {
  const float* X      = (const float*)d_in[0];
  const float* dw1_w  = (const float*)d_in[1];
  const float* dw1_b  = (const float*)d_in[2];
  const float* bn_dw1 = (const float*)d_in[3];
  const float* f1_w   = (const float*)d_in[4];
  const float* f1_b   = (const float*)d_in[5];
  const float* f2_w   = (const float*)d_in[6];
  const float* f2_b   = (const float*)d_in[7];
  const float* g_w    = (const float*)d_in[8];
  const float* g_b    = (const float*)d_in[9];
  const float* bn_g   = (const float*)d_in[10];
  const float* dw2_w  = (const float*)d_in[11];
  const float* dw2_b  = (const float*)d_in[12];
  const float* hatt1w = (const float*)d_in[13];
  const float* vatt1w = (const float*)d_in[14];
  const float* hatt2w = (const float*)d_in[15];
  const float* vatt2w = (const float*)d_in[16];
  const float* bn_mra = (const float*)d_in[17];
  const float* bcdt_w = (const float*)d_in[18];
  const float* ssd_dw = (const float*)d_in[19];
  const float* hz_w   = (const float*)d_in[20];
  const float* out_w  = (const float*)d_in[21];
  const float* D_p    = (const float*)d_in[23];
  const float* qkv_w  = (const float*)d_in[24];
  const float* proj_w = (const float*)d_in[25];
  const float* bn_n4  = (const float*)d_in[26];
  const float* mlp1_w = (const float*)d_in[27];
  const float* bn_mlp = (const float*)d_in[28];
  const float* mlp2_w = (const float*)d_in[29];
  const float* bn_n1  = (const float*)d_in[30];

  float* ws   = (float*)d_ws;
  float* x1o  = ws+OFF_X1O;  float* t1  = ws+OFF_T1;  float* t2  = ws+OFF_T2;
  float* xa   = ws+OFF_XA;   float* bc1 = ws+OFF_BC1; float* bc2 = ws+OFF_BC2;
  float* wgt  = ws+OFF_WGT;  float* h0  = ws+OFF_H;   float* h1  = ws+OFF_H2;
  float* ho   = ws+OFF_HO;   float* qkvb= ws+OFF_QKV; float* obuf= ws+OFF_O;
  float* lsb  = ws+OFF_LS;   float* mid = ws+OFF_MID;

  dim3 blk(256);
  #define NB(n) dim3((unsigned)(((n)+255)/256))
  const int NCL = B*C*LPIX;

  // zero attention accumulators (obuf + lsb are contiguous)
  hipMemsetAsync(obuf, 0, ((size_t)B*LPIX*C + (size_t)B*NH*LPIX)*sizeof(float), stream);

  // branch 1
  k_dw1  <<<NB(NCL),blk,0,stream>>>(X,dw1_w,dw1_b,bn_dw1,x1o);
  k_star <<<NB(B*(HID/4)*LPIX),blk,0,stream>>>(x1o,f1_w,f1_b,f2_w,f2_b,t1);
  k_gproj<<<NB(B*(C/4)*LPIX),blk,0,stream>>>(t1,g_w,g_b,bn_g,t2);
  k_dw2  <<<NB(NCL),blk,0,stream>>>(t2,dw2_w,dw2_b,xa);
  // branch 2 (fused)
  k_branch2<<<dim3(B*C),blk,0,stream>>>(X,hatt1w,vatt1w,hatt2w,vatt2w,bn_mra,xa);
  // branch 3
  k_bcdt <<<NB(B*48*LPIX),blk,0,stream>>>(X,bcdt_w,bc1);
  k_ssddw<<<NB(B*192*LPIX),blk,0,stream>>>(bc1,ssd_dw,bc2);
  k_ssd_softmax<<<dim3(B*S),blk,0,stream>>>(bc2,wgt);
  k_h    <<<dim3(B*32),blk,0,stream>>>(X,wgt,h0,h1);
  k_mixho<<<dim3(B*8),blk,0,stream>>>(h0,h1,hz_w,D_p,out_w,ho);
  k_x3   <<<NB(NCL),blk,0,stream>>>(ho,bc2,xa);
  // branch 4
  k_qkv  <<<NB(B*48*LPIX),blk,0,stream>>>(X,qkv_w,qkvb);
  k_attn <<<dim3(B*NH*8),blk,0,stream>>>(qkvb,obuf,lsb);
  k_x4   <<<NB(B*(C/4)*LPIX),blk,0,stream>>>(X,obuf,lsb,proj_w,bn_n4,xa);
  // merge MLP
  k_mid  <<<NB(B*(HID/4)*LPIX),blk,0,stream>>>(xa,mlp1_w,bn_mlp,mid);
  k_out  <<<NB(B*(DIM/4)*LPIX),blk,0,stream>>>(X,mid,mlp2_w,bn_n1,(float*)d_out);
  #undef NB
}

// Round 9
// 344.031 us; speedup vs baseline: 1.3561x; 1.3561x over previous
//
#include <hip/hip_runtime.h>
#include <hip/hip_bf16.h>
#include <math.h>

#define DEV __device__ __forceinline__

constexpr int B=8, C=64, DIM=256, HID=128, S=64, NH=16, HD=4, LPIX=784;

constexpr size_t OFF_X1O = 0;                                   // B*C*L
constexpr size_t OFF_T1  = OFF_X1O + (size_t)B*C*LPIX;          // B*HID*L
constexpr size_t OFF_T2  = OFF_T1  + (size_t)B*HID*LPIX;        // B*C*L
constexpr size_t OFF_XA  = OFF_T2  + (size_t)B*C*LPIX;          // B*DIM*L
constexpr size_t OFF_BC1 = OFF_XA  + (size_t)B*DIM*LPIX;        // B*192*L
constexpr size_t OFF_BC2 = OFF_BC1 + (size_t)B*192*LPIX;        // B*192*L
constexpr size_t OFF_WGT = OFF_BC2 + (size_t)B*192*LPIX;        // B*S*L
constexpr size_t OFF_H   = OFF_WGT + (size_t)B*S*LPIX;          // B*C*S (partial 0)
constexpr size_t OFF_H2  = OFF_H   + (size_t)B*C*S;             // B*C*S (partial 1)
constexpr size_t OFF_HO  = OFF_H2  + (size_t)B*C*S;             // B*C*S
constexpr size_t OFF_QKV = OFF_HO  + (size_t)B*C*S;             // 3*B*NH*L*HD
constexpr size_t OFF_O   = OFF_QKV + (size_t)3*B*NH*LPIX*HD;    // B*L*C (normalized)
constexpr size_t OFF_MID = OFF_O   + (size_t)B*LPIX*C;          // B*HID*L

DEV float bnorm(float x, const float* p, int c, int nc){
  float g=p[c], bb=p[nc+c], m=p[2*nc+c], v=p[3*nc+c];
  return (x-m)*(g*rsqrtf(v+1e-5f))+bb;
}
DEV int refl(int p){ int k=p-1; if(k<0)k=-k; if(k>27)k=54-k; return k; }

// ================= bodies =================
DEV void body_dw1(int idx, const float* X, const float* w, const float* bias, const float* bnp, float* out){
  if(idx>=B*C*LPIX) return;
  int l=idx%LPIX, c=(idx/LPIX)%C, b=idx/(LPIX*C);
  int y=l/28, x=l%28;
  const float* xp = X + ((size_t)(b*DIM+c))*LPIX;
  float s = bias[c];
  for(int ky=0;ky<7;ky++){ int iy=y+ky-3; if(iy<0||iy>=28) continue;
    for(int kx=0;kx<7;kx++){ int ix=x+kx-3; if(ix<0||ix>=28) continue;
      s += xp[(size_t)iy*28+ix]*w[(size_t)c*49+ky*7+kx]; } }
  out[idx] = bnorm(s,bnp,c,C);
}

DEV void body_branch2(int bc, int tid, float* smem, const float* X,
                      const float* h1w,const float* v1w,const float* h2w,const float* v2w,
                      const float* bnp, float* xa){
  int c = bc & 63, b = bc >> 6;
  float* xs  = smem;          // 784
  float* mp  = smem+LPIX;     // 784
  float* xt  = smem+2*LPIX;   // 100
  float* attv= smem+2*LPIX+100;
  const float* xp = X + ((size_t)(b*DIM+64+c))*LPIX;
  for(int i=tid;i<LPIX;i+=256) xs[i]=xp[i];
  __syncthreads();
  for(int i=tid;i<LPIX;i+=256){
    int y=i/28, x=i%28;
    float m=-1e30f;
    for(int dy=-1;dy<=1;dy++){ int iy=y+dy; if(iy<0||iy>=28) continue;
      for(int dx=-1;dx<=1;dx++){ int ix=x+dx; if(ix<0||ix>=28) continue;
        m=fmaxf(m,xs[iy*28+ix]); } }
    mp[i]=m;
  }
  __syncthreads();
  if(tid<100){
    int ii=tid/10, j=tid%10;
    const float fw[4]={0.125f,0.375f,0.375f,0.125f};
    float s=0;
    for(int ky=0;ky<4;ky++){ int rr=refl(3*ii+ky);
      for(int kx=0;kx<4;kx++){ int cc=refl(3*j+kx);
        s += fw[ky]*fw[kx]*mp[rr*28+cc]; } }
    xt[tid]=s;
  }
  __syncthreads();
  if(tid<100){
    int r=tid/10, j=tid%10;
    float s=0;
    for(int kh=0;kh<11;kh++){ int a=r+kh-5; if(a<0||a>=10) continue;
      for(int kw=0;kw<3;kw++){ int b2=j+kw-1; if(b2<0||b2>=10) continue;
        s+=xt[a*10+b2]*h1w[(size_t)c*33+kh*3+kw]; } }
    for(int kh=0;kh<3;kh++){ int a=r+kh-1; if(a<0||a>=10) continue;
      for(int kw=0;kw<11;kw++){ int b2=j+kw-5; if(b2<0||b2>=10) continue;
        s+=xt[a*10+b2]*v1w[(size_t)c*33+kh*11+kw]; } }
    { int t=20*r+j; int r2=t/19, j2=t%19;
      for(int kh=0;kh<11;kh++){ int a=r2+kh-5; if(a<0||a>=10) continue;
        for(int kw=0;kw<3;kw++){ int b2=j2+kw-1; if(b2<0||b2>=19) continue;
          int i2=19*a+b2; int row=i2/20, col=i2%20;
          if(col<10) s+=xt[row*10+col]*h2w[(size_t)c*33+kh*3+kw]; } } }
    { int t=20*j+r; int p=t%19, q=t/19;
      for(int kh=0;kh<3;kh++){ int a=p+kh-1; if(a<0||a>=19) continue;
        for(int kw=0;kw<11;kw++){ int b2=q+kw-5; if(b2<0||b2>=10) continue;
          int i2=19*b2+a; int row=i2/20, col=i2%20;
          if(col<10) s+=xt[col*10+row]*v2w[(size_t)c*33+kh*11+kw]; } } }
    s = bnorm(s,bnp,c,C);
    attv[tid] = 1.f/(1.f+__expf(-s));
  }
  __syncthreads();
  float* dst = xa + ((size_t)(b*DIM+64+c))*LPIX;
  for(int i=tid;i<LPIX;i+=256){
    int y=i/28, x=i%28;
    float a = attv[((y*10)/28)*10 + (x*10)/28];
    dst[i] = xs[i]*a;
  }
}

DEV void body_pw64x4(int idx, const float* X, int coff, const float* w, float* dst4base, int mode, float* qkvb){
  // mode 0: bc1-style write; mode 1: qkv write
  if(idx>=B*48*LPIX) return;
  int l=idx%LPIX, og=(idx/LPIX)%48, b=idx/(LPIX*48);
  int o0=og*4;
  const float* xp = X + ((size_t)(b*DIM+coff))*LPIX + l;
  float s[4]={0,0,0,0};
  for(int c=0;c<C;c++){ float xv=xp[(size_t)c*LPIX];
    for(int t=0;t<4;t++) s[t]+=w[(size_t)(o0+t)*C+c]*xv; }
  if(mode==0){
    for(int t=0;t<4;t++) dst4base[((size_t)(b*192+o0+t))*LPIX+l]=s[t];
  } else {
    int which=o0>>6, rem=o0&63, head=rem>>2;
    float4* dst = (float4*)(qkvb + (size_t)which*B*NH*LPIX*HD + ((size_t)((b*NH+head)*LPIX+l))*HD);
    *dst = make_float4(s[0],s[1],s[2],s[3]);
  }
}

// attention: rowseg=4, full K/V in LDS, normalized output, exp2-prescaled q
DEV void body_attn(int blk, int tid, float4* ks, float4* vs,
                   const float* qkvb, float* obuf){
  int bh = blk >> 2, seg = blk & 3;
  int b = bh>>4, h = bh&15;
  const float4* q4 = (const float4*)(qkvb + (size_t)bh*LPIX*HD);
  const float4* k4 = (const float4*)(qkvb + (size_t)(B*NH + bh)*LPIX*HD);
  const float4* v4 = (const float4*)(qkvb + (size_t)(2*B*NH + bh)*LPIX*HD);
  for(int i=tid;i<LPIX;i+=256){ ks[i]=k4[i]; vs[i]=v4[i]; }
  __syncthreads();
  if(tid>=196) return;
  int r = seg*196 + tid;
  float4 qa = q4[r];
  const float SC = 0.5f*1.44269504f;  // fold 1/sqrt(HD) and log2(e) into q
  qa.x*=SC; qa.y*=SC; qa.z*=SC; qa.w*=SC;
  float ls=0,a0=0,a1=0,a2=0,a3=0;
  #pragma unroll 4
  for(int m=0;m<LPIX;m++){
    float4 kv = ks[m]; float4 vv = vs[m];
    float sc = qa.x*kv.x+qa.y*kv.y+qa.z*kv.z+qa.w*kv.w;
    float p = exp2f(sc);
    ls+=p; a0+=p*vv.x; a1+=p*vv.y; a2+=p*vv.z; a3+=p*vv.w;
  }
  float inv = 1.f/ls;
  float4* op = (float4*)(obuf + ((size_t)(b*LPIX+r))*C + h*4);
  *op = make_float4(a0*inv,a1*inv,a2*inv,a3*inv);
}

DEV void body_star(int idx, const float* x1o, const float* f1w,const float* f1b,const float* f2w,const float* f2b,float* t1){
  if(idx>=B*(HID/4)*LPIX) return;
  int l=idx%LPIX, jg=(idx/LPIX)%(HID/4), b=idx/(LPIX*(HID/4));
  int j0=jg*4;
  const float* xp = x1o + (size_t)b*C*LPIX + l;
  float a[4], g[4];
  for(int t=0;t<4;t++){ a[t]=f1b[j0+t]; g[t]=f2b[j0+t]; }
  for(int c=0;c<C;c++){
    float xv = xp[(size_t)c*LPIX];
    for(int t=0;t<4;t++){ a[t]+=f1w[(size_t)(j0+t)*C+c]*xv; g[t]+=f2w[(size_t)(j0+t)*C+c]*xv; }
  }
  for(int t=0;t<4;t++){
    float av = fminf(fmaxf(a[t],0.f),6.f);
    t1[((size_t)(b*HID+j0+t))*LPIX + l] = av*g[t];
  }
}

DEV void body_ssddw(int idx, const float* bc1, const float* w, float* bc2){
  if(idx>=B*192*LPIX) return;
  int l=idx%LPIX, ch=(idx/LPIX)%192, b=idx/(LPIX*192);
  int y=l/28, x=l%28;
  const float* p = bc1 + (size_t)(b*192+ch)*LPIX;
  float s=0;
  for(int ky=0;ky<3;ky++){ int iy=y+ky-1; if(iy<0||iy>=28) continue;
    for(int kx=0;kx<3;kx++){ int ix=x+kx-1; if(ix<0||ix>=28) continue;
      s += p[(size_t)iy*28+ix]*w[(size_t)ch*9+ky*3+kx]; } }
  bc2[idx]=s;
}

DEV void body_gproj(int idx, const float* t1, const float* gw,const float* gb,const float* bnp,float* t2){
  if(idx>=B*(C/4)*LPIX) return;
  int l=idx%LPIX, cg=(idx/LPIX)%(C/4), b=idx/(LPIX*(C/4));
  int c0=cg*4;
  const float* tp = t1 + (size_t)b*HID*LPIX + l;
  float s[4]; for(int t=0;t<4;t++) s[t]=gb[c0+t];
  for(int j=0;j<HID;j++){
    float xv = tp[(size_t)j*LPIX];
    for(int t=0;t<4;t++) s[t]+=gw[(size_t)(c0+t)*HID+j]*xv;
  }
  for(int t=0;t<4;t++) t2[((size_t)(b*C+c0+t))*LPIX + l]=bnorm(s[t],bnp,c0+t,C);
}

DEV void body_softmax(int bs, int tid, float* smem, const float* bc2, float* wgt){
  int b=bs>>6, s_=bs&63;
  const float* dt = bc2 + ((size_t)(b*192+128+s_))*LPIX;
  const float* Bm = bc2 + ((size_t)(b*192+s_))*LPIX;
  float* row = smem;         // 784
  float* red = smem+LPIX;    // 256
  int t=tid;
  float mx=-1e30f;
  for(int l=t;l<LPIX;l+=256){ float v=dt[l]; row[l]=v; mx=fmaxf(mx,v); }
  red[t]=mx; __syncthreads();
  for(int o=128;o>0;o>>=1){ if(t<o) red[t]=fmaxf(red[t],red[t+o]); __syncthreads(); }
  mx=red[0]; __syncthreads();
  float sum=0;
  for(int l=t;l<LPIX;l+=256){ float e=__expf(row[l]-mx); row[l]=e; sum+=e; }
  red[t]=sum; __syncthreads();
  for(int o=128;o>0;o>>=1){ if(t<o) red[t]+=red[t+o]; __syncthreads(); }
  float inv=1.f/red[0];
  for(int l=t;l<LPIX;l+=256) wgt[((size_t)(b*S+s_))*LPIX+l] = row[l]*inv*Bm[l];
}

DEV void body_x4(int idx, const float* X, const float* obuf, const float* projw, const float* bnp, float* xa){
  if(idx>=B*(C/4)*LPIX) return;
  int l=idx%LPIX, cg=(idx/LPIX)%(C/4), b=idx/(LPIX*(C/4));
  int c0=cg*4;
  const float* op = obuf + ((size_t)(b*LPIX+l))*C;
  float s[4]={0,0,0,0};
  for(int k=0;k<C;k++){ float ov=op[k];
    for(int t=0;t<4;t++) s[t]+=projw[(size_t)(c0+t)*C+k]*ov; }
  for(int t=0;t<4;t++){
    float v = s[t] + X[((size_t)(b*DIM+192+c0+t))*LPIX + l];
    xa[((size_t)(b*DIM+192+c0+t))*LPIX + l] = bnorm(v,bnp,c0+t,C);
  }
}

DEV void body_h(int blk, int tid, float* smem, const float* X, const float* wgt, float* h0, float* h1){
  int sub = blk & 31; int b = blk >> 5;
  int tile = sub >> 1, half = sub & 1;
  int ct = (tile>>2)*16, st = (tile&3)*16;
  int l0 = half*392;
  float (*Xs)[393] = (float(*)[393])smem;
  float (*Ws)[393] = (float(*)[393])(smem + 16*393);
  for(int i=tid;i<16*392;i+=256){
    int r=i/392, col=i%392;
    Xs[r][col] = X[((size_t)(b*DIM+128+ct+r))*LPIX + l0 + col];
    Ws[r][col] = wgt[((size_t)(b*S+st+r))*LPIX + l0 + col];
  }
  __syncthreads();
  int tc = tid>>4, ts = tid&15;
  float acc=0;
  #pragma unroll 4
  for(int l=0;l<392;l++) acc += Xs[tc][l]*Ws[ts][l];
  float* dst = half ? h1 : h0;
  dst[((size_t)(b*C+ct+tc))*S + st+ts] = acc;
}

DEV void body_dw2(int idx, const float* t2,const float* w,const float* bias,float* xa){
  if(idx>=B*C*LPIX) return;
  int l=idx%LPIX, c=(idx/LPIX)%C, b=idx/(LPIX*C);
  int y=l/28, x=l%28;
  const float* tp = t2 + ((size_t)(b*C+c))*LPIX;
  float s=bias[c];
  for(int ky=0;ky<7;ky++){ int iy=y+ky-3; if(iy<0||iy>=28) continue;
    for(int kx=0;kx<7;kx++){ int ix=x+kx-3; if(ix<0||ix>=28) continue;
      s += tp[(size_t)iy*28+ix]*w[(size_t)c*49+ky*7+kx]; } }
  xa[((size_t)(b*DIM+c))*LPIX + l] = s;
}

// ================= stage kernels =================
// S1: dep X only.  [0,512)=branch2  [512,2080)=dw1  [2080,3256)=bcdt  [3256,4432)=qkv
__global__ void k_s1(const float* X,
                     const float* h1w,const float* v1w,const float* h2w,const float* v2w,const float* bn_mra,
                     const float* dw1_w,const float* dw1_b,const float* bn_dw1,
                     const float* bcdt_w, const float* qkv_w,
                     float* xa, float* x1o, float* bc1, float* qkvb){
  __shared__ float smem[2*LPIX+200];
  int blk = blockIdx.x, tid = threadIdx.x;
  if(blk < 512)       body_branch2(blk, tid, smem, X, h1w,v1w,h2w,v2w, bn_mra, xa);
  else if(blk < 2080) body_dw1((blk-512)*256+tid, X, dw1_w, dw1_b, bn_dw1, x1o);
  else if(blk < 3256) body_pw64x4((blk-2080)*256+tid, X, 128, bcdt_w, bc1, 0, nullptr);
  else                body_pw64x4((blk-3256)*256+tid, X, 192, qkv_w, nullptr, 1, qkvb);
}

// S2: [0,512)=attn  [512,1296)=star  [1296,6000)=ssddw
__global__ void k_s2(const float* qkvb, float* obuf,
                     const float* x1o, const float* f1w,const float* f1b,const float* f2w,const float* f2b, float* t1,
                     const float* bc1, const float* ssd_dw, float* bc2){
  __shared__ float4 ks[LPIX];
  __shared__ float4 vs[LPIX];
  int blk = blockIdx.x, tid = threadIdx.x;
  if(blk < 512)        body_attn(blk, tid, ks, vs, qkvb, obuf);
  else if(blk < 1296)  body_star((blk-512)*256+tid, x1o, f1w,f1b,f2w,f2b, t1);
  else                 body_ssddw((blk-1296)*256+tid, bc1, ssd_dw, bc2);
}

// S3: [0,512)=softmax  [512,904)=gproj  [904,1296)=x4
__global__ void k_s3(const float* bc2, float* wgt,
                     const float* t1, const float* gw,const float* gb,const float* bn_g, float* t2,
                     const float* X, const float* obuf, const float* projw, const float* bn_n4, float* xa){
  __shared__ float smem[LPIX+256];
  int blk = blockIdx.x, tid = threadIdx.x;
  if(blk < 512)       body_softmax(blk, tid, smem, bc2, wgt);
  else if(blk < 904)  body_gproj((blk-512)*256+tid, t1, gw, gb, bn_g, t2);
  else                body_x4((blk-904)*256+tid, X, obuf, projw, bn_n4, xa);
}

// S4: [0,256)=h  [256,1824)=dw2
__global__ void k_s4(const float* X, const float* wgt, float* h0, float* h1,
                     const float* t2, const float* dw2_w, const float* dw2_b, float* xa){
  __shared__ float smem[2*16*393];
  int blk = blockIdx.x, tid = threadIdx.x;
  if(blk < 256) body_h(blk, tid, smem, X, wgt, h0, h1);
  else          body_dw2((blk-256)*256+tid, t2, dw2_w, dw2_b, xa);
}

__global__ void k_mixho(const float* h0, const float* h1, const float* hzw, const float* Dp, const float* outw, float* ho){
  int b = blockIdx.x >> 3, st = (blockIdx.x & 7) * 8;
  __shared__ float hs2[C][8];
  __shared__ float g1s[C][8];
  for(int i=threadIdx.x;i<C*8;i+=256){
    int k=i>>3, si=i&7;
    size_t off = ((size_t)(b*C+k))*S + st + si;
    hs2[k][si] = h0[off] + h1[off];
  }
  __syncthreads();
  float D = Dp[0];
  for(int i=threadIdx.x;i<C*8;i+=256){
    int c=i>>3, si=i&7;
    float hv=0, zv=0;
    for(int k=0;k<C;k++){ float x=hs2[k][si]; hv+=hzw[(size_t)c*C+k]*x; zv+=hzw[(size_t)(C+c)*C+k]*x; }
    float sil = zv/(1.f+__expf(-zv));
    g1s[c][si]=hv*sil+hv*D;
  }
  __syncthreads();
  for(int i=threadIdx.x;i<C*8;i+=256){
    int c=i>>3, si=i&7;
    float acc=0;
    for(int k=0;k<C;k++) acc+=outw[(size_t)c*C+k]*g1s[k][si];
    ho[((size_t)(b*C+c))*S + st + si]=acc;
  }
}

__global__ void k_x3(const float* ho, const float* bc2, float* xa){
  int idx = blockIdx.x*256+threadIdx.x; if(idx>=B*C*LPIX) return;
  int l=idx%LPIX, c=(idx/LPIX)%C, b=idx/(LPIX*C);
  const float* hp = ho + (size_t)(b*C+c)*S;
  const float* cm = bc2 + ((size_t)(b*192+64))*LPIX + l;
  float acc=0;
  for(int s_=0;s_<S;s_++) acc += hp[s_]*cm[(size_t)s_*LPIX];
  xa[((size_t)(b*DIM+128+c))*LPIX + l] = acc;
}

__global__ void k_mid(const float* xa, const float* m1w, const float* bnp, float* mid){
  int idx = blockIdx.x*256+threadIdx.x; if(idx>=B*(HID/4)*LPIX) return;
  int l=idx%LPIX, jg=(idx/LPIX)%(HID/4), b=idx/(LPIX*(HID/4));
  int j0=jg*4;
  const float* xp = xa + (size_t)b*DIM*LPIX + l;
  float s[4]={0,0,0,0};
  for(int c=0;c<DIM;c++){ float xv=xp[(size_t)c*LPIX];
    for(int t=0;t<4;t++) s[t]+=m1w[(size_t)(j0+t)*DIM+c]*xv; }
  for(int t=0;t<4;t++)
    mid[((size_t)(b*HID+j0+t))*LPIX + l] = fmaxf(bnorm(s[t],bnp,j0+t,HID),0.f);
}

__global__ void k_out(const float* X, const float* mid, const float* m2w, const float* bnp, float* out){
  int idx = blockIdx.x*256+threadIdx.x; if(idx>=B*(DIM/4)*LPIX) return;
  int l=idx%LPIX, cg=(idx/LPIX)%(DIM/4), b=idx/(LPIX*(DIM/4));
  int c0=cg*4;
  const float* mp_ = mid + (size_t)b*HID*LPIX + l;
  float s[4]={0,0,0,0};
  for(int j=0;j<HID;j++){ float mv=mp_[(size_t)j*LPIX];
    for(int t=0;t<4;t++) s[t]+=m2w[(size_t)(c0+t)*HID+j]*mv; }
  for(int t=0;t<4;t++){
    size_t oi = ((size_t)(b*DIM+c0+t))*LPIX + l;
    out[oi] = bnorm(s[t],bnp,c0+t,DIM) + X[oi];
  }
}

extern "C" void kernel_launch(void* const* d_in, const int* in_sizes, int n_in,
                              void* d_out, int out_size, void* d_ws, size_t ws_size,
                              hipStream_t stream) {
  const float* X      = (const float*)d_in[0];
  const float* dw1_w  = (const float*)d_in[1];
  const float* dw1_b  = (const float*)d_in[2];
  const float* bn_dw1 = (const float*)d_in[3];
  const float* f1_w   = (const float*)d_in[4];
  const float* f1_b   = (const float*)d_in[5];
  const float* f2_w   = (const float*)d_in[6];
  const float* f2_b   = (const float*)d_in[7];
  const float* g_w    = (const float*)d_in[8];
  const float* g_b    = (const float*)d_in[9];
  const float* bn_g   = (const float*)d_in[10];
  const float* dw2_w  = (const float*)d_in[11];
  const float* dw2_b  = (const float*)d_in[12];
  const float* hatt1w = (const float*)d_in[13];
  const float* vatt1w = (const float*)d_in[14];
  const float* hatt2w = (const float*)d_in[15];
  const float* vatt2w = (const float*)d_in[16];
  const float* bn_mra = (const float*)d_in[17];
  const float* bcdt_w = (const float*)d_in[18];
  const float* ssd_dw = (const float*)d_in[19];
  const float* hz_w   = (const float*)d_in[20];
  const float* out_w  = (const float*)d_in[21];
  const float* D_p    = (const float*)d_in[23];
  const float* qkv_w  = (const float*)d_in[24];
  const float* proj_w = (const float*)d_in[25];
  const float* bn_n4  = (const float*)d_in[26];
  const float* mlp1_w = (const float*)d_in[27];
  const float* bn_mlp = (const float*)d_in[28];
  const float* mlp2_w = (const float*)d_in[29];
  const float* bn_n1  = (const float*)d_in[30];

  float* ws   = (float*)d_ws;
  float* x1o  = ws+OFF_X1O;  float* t1  = ws+OFF_T1;  float* t2  = ws+OFF_T2;
  float* xa   = ws+OFF_XA;   float* bc1 = ws+OFF_BC1; float* bc2 = ws+OFF_BC2;
  float* wgt  = ws+OFF_WGT;  float* h0  = ws+OFF_H;   float* h1  = ws+OFF_H2;
  float* ho   = ws+OFF_HO;   float* qkvb= ws+OFF_QKV; float* obuf= ws+OFF_O;
  float* mid  = ws+OFF_MID;

  dim3 blk(256);
  #define NB(n) dim3((unsigned)(((n)+255)/256))

  k_s1   <<<dim3(4432),blk,0,stream>>>(X, hatt1w,vatt1w,hatt2w,vatt2w,bn_mra,
                                       dw1_w,dw1_b,bn_dw1, bcdt_w, qkv_w,
                                       xa, x1o, bc1, qkvb);
  k_s2   <<<dim3(6000),blk,0,stream>>>(qkvb, obuf,
                                       x1o, f1_w,f1_b,f2_w,f2_b, t1,
                                       bc1, ssd_dw, bc2);
  k_s3   <<<dim3(1296),blk,0,stream>>>(bc2, wgt,
                                       t1, g_w,g_b,bn_g, t2,
                                       X, obuf, proj_w, bn_n4, xa);
  k_s4   <<<dim3(1824),blk,0,stream>>>(X, wgt, h0, h1, t2, dw2_w, dw2_b, xa);
  k_mixho<<<dim3(B*8),blk,0,stream>>>(h0,h1,hz_w,D_p,out_w,ho);
  k_x3   <<<NB(B*C*LPIX),blk,0,stream>>>(ho,bc2,xa);
  k_mid  <<<NB(B*(HID/4)*LPIX),blk,0,stream>>>(xa,mlp1_w,bn_mlp,mid);
  k_out  <<<NB(B*(DIM/4)*LPIX),blk,0,stream>>>(X,mid,mlp2_w,bn_n1,(float*)d_out);
  #undef NB
}